// Round 19
// baseline (129.821 us; speedup 1.0000x reference)
//
#include <hip/hip_runtime.h>

// ===========================================================================
// R19: R18 with conv4 folded in: conv1234_k (512 blk, block = one splat
// pixel; halo chain x1 15x15x8 -> x2 7x7x16 -> x3 3x3x32 -> splat 1x1x64).
// 5 levels: conv1234, l1||g1, loc||g2, fcfusion96, slice.
// Ledger: ~12us/level; WIDE beats fused-narrow (R8/R14-R16); level duration =
// slowest block; branch-role fusion shares worst-case VGPR/LDS (R17); no
// serial wave-reduce chains (R10); no grid.sync (R7); FC thread-per-output
// needs transposed weights + waves (R12-R14); small weights L1-hot (R15).
// ===========================================================================

#define LUT_NB   512
#define LUT_LO   (-0.25f)
#define LUT_BIN  (1.5f / LUT_NB)
#define LUT_INV  (LUT_NB / 1.5f)

// ---------------------------------------------------------------------------
// L1: conv1+conv2+conv3+conv4 halo-fused. Block = (n, splat pixel). 512 blk.
// ---------------------------------------------------------------------------
__global__ void __launch_bounds__(256) conv1234_k(
    const float* __restrict__ lowres,
    const float* __restrict__ sw1, const float* __restrict__ sb1,
    const float* __restrict__ sw2, const float* __restrict__ sb2,
    const float* __restrict__ sw3, const float* __restrict__ sb3,
    const float* __restrict__ sw4, const float* __restrict__ sb4,
    const float* __restrict__ thr, const float* __restrict__ slp,
    const float* __restrict__ fw3, const float* __restrict__ fw4,
    const float* __restrict__ fw5,
    float* __restrict__ splat, float2* __restrict__ lut,
    float* __restrict__ fwt3, float* __restrict__ fwt4,
    float* __restrict__ fwt5)
{
    __shared__ float s_x1[15 * 15 * 8];    // 7.0KB
    __shared__ float s_x2[7 * 7 * 16];     // 3.1KB
    __shared__ float s_x3[3 * 3 * 32];     // 1.1KB
    const int tid = threadIdx.x;
    const int n   = blockIdx.x >> 8;
    const int pix = blockIdx.x & 255;
    const int sy  = pix >> 4, sx = pix & 15;

    // ---- one-time weight transposes (spread over 512 blocks) ----
    {
        int tg = blockIdx.x * 256 + tid;           // 0..131071
        #pragma unroll
        for (int r = 0; r < 2; ++r) {
            int e = tg + r * 131072;
            int o = e & 255, k = e >> 8;
            fwt3[e] = fw3[o * 1024 + k];
        }
        if (tg < 32768) {
            int o = tg & 127, k = tg >> 7;
            fwt4[tg] = fw4[o * 256 + k];
        }
        if (tg < 8192) {
            int o = tg & 63, k = tg >> 6;
            fwt5[tg] = fw5[o * 128 + k];
        }
    }
    if (blockIdx.x == 0) {
        for (int e = tid; e < 3 * LUT_NB; e += 256) {
            int j = e >> 9;
            int i = e & (LUT_NB - 1);
            float xl = LUT_LO + i * LUT_BIN;
            float xh = xl + LUT_BIN;
            float a = 0.0f, c = 0.0f;
            #pragma unroll
            for (int k = 0; k < 16; ++k) {
                float tt = thr[j * 16 + k], ss = slp[j * 16 + k];
                a = fmaf(ss, fmaxf(xl - tt, 0.0f), a);
                c = fmaf(ss, fmaxf(xh - tt, 0.0f), c);
            }
            lut[e] = make_float2(a, c - a);
        }
    }

    const int b1h = 8 * sy - 7, b1w = 8 * sx - 7;   // x1 halo origin (15)
    const int b2h = 4 * sy - 3, b2w = 4 * sx - 3;   // x2 halo origin (7)
    const int b3h = 2 * sy - 1, b3w = 2 * sx - 1;   // x3 halo origin (3)

    // Phase A: x1 halo 15x15x8 (conv1 from lowres)
    for (int i = tid; i < 1800; i += 256) {
        int c   = i & 7;
        int pos = i >> 3;
        int lw  = pos % 15, lh = pos / 15;
        int gh  = b1h + lh, gw = b1w + lw;
        float v = 0.0f;
        if (gh >= 0 && gh < 128 && gw >= 0 && gw < 128) {
            float acc = sb1[c];
            #pragma unroll
            for (int ci = 0; ci < 3; ++ci) {
                const float* ib = lowres + ((size_t)(n * 3 + ci)) * 65536;
                const float* wb = sw1 + ((size_t)c * 3 + ci) * 9;
                #pragma unroll
                for (int kh = 0; kh < 3; ++kh) {
                    int ih = 2 * gh - 1 + kh;
                    if (ih < 0 || ih >= 256) continue;
                    #pragma unroll
                    for (int kw = 0; kw < 3; ++kw) {
                        int iw = 2 * gw - 1 + kw;
                        if (iw < 0 || iw >= 256) continue;
                        acc = fmaf(ib[ih * 256 + iw], wb[kh * 3 + kw], acc);
                    }
                }
            }
            v = fmaxf(acc, 0.0f);
        }
        s_x1[i] = v;
    }
    __syncthreads();

    // Phase B: x2 halo 7x7x16 (conv2 from s_x1)
    for (int i = tid; i < 784; i += 256) {
        int c   = i & 15;
        int pos = i >> 4;
        int lw  = pos % 7, lh = pos / 7;
        int gh  = b2h + lh, gw = b2w + lw;
        float v = 0.0f;
        if (gh >= 0 && gh < 64 && gw >= 0 && gw < 64) {
            float acc = sb2[c];
            const float* wb = sw2 + (size_t)c * 72;
            #pragma unroll
            for (int kh = 0; kh < 3; ++kh) {
                #pragma unroll
                for (int kw = 0; kw < 3; ++kw) {
                    const float* xp = &s_x1[((2 * lh + kh) * 15 + 2 * lw + kw) * 8];
                    const float* wp = wb + kh * 3 + kw;
                    #pragma unroll
                    for (int ci = 0; ci < 8; ++ci)
                        acc = fmaf(xp[ci], wp[ci * 9], acc);
                }
            }
            v = fmaxf(acc, 0.0f);
        }
        s_x2[i] = v;
    }
    __syncthreads();

    // Phase C: x3 halo 3x3x32 (conv3 from s_x2)
    for (int i = tid; i < 288; i += 256) {
        int c   = i & 31;
        int pos = i >> 5;
        int lw  = pos % 3, lh = pos / 3;
        int gh  = b3h + lh, gw = b3w + lw;
        float v = 0.0f;
        if (gh >= 0 && gh < 32 && gw >= 0 && gw < 32) {
            float acc = sb3[c];
            const float* wb = sw3 + (size_t)c * 144;
            #pragma unroll
            for (int kh = 0; kh < 3; ++kh) {
                #pragma unroll
                for (int kw = 0; kw < 3; ++kw) {
                    const float* xp = &s_x2[((2 * lh + kh) * 7 + 2 * lw + kw) * 16];
                    const float* wp = wb + kh * 3 + kw;
                    #pragma unroll
                    for (int ci = 0; ci < 16; ++ci)
                        acc = fmaf(xp[ci], wp[ci * 9], acc);
                }
            }
            v = fmaxf(acc, 0.0f);
        }
        s_x3[i] = v;
    }
    __syncthreads();

    // Phase D: splat 1x1x64 (conv4 from s_x3) -> global HWC
    if (tid < 64) {
        float acc = sb4[tid];
        const float* wb = sw4 + (size_t)tid * 288;
        #pragma unroll
        for (int kh = 0; kh < 3; ++kh) {
            #pragma unroll
            for (int kw = 0; kw < 3; ++kw) {
                const float* xp = &s_x3[(kh * 3 + kw) * 32];
                const float* wp = wb + kh * 3 + kw;
                #pragma unroll
                for (int ci = 0; ci < 32; ++ci)
                    acc = fmaf(xp[ci], wp[ci * 9], acc);
            }
        }
        splat[((size_t)(n * 16 + sy) * 16 + sx) * 64 + tid] = fmaxf(acc, 0.0f);
    }
}

// ---------------------------------------------------------------------------
// CIN=64 wave-conv, ONE output per wave.
// ---------------------------------------------------------------------------
__device__ __forceinline__ void convw64_one(const float* __restrict__ in,
                                            const float* __restrict__ wgt,
                                            const float* __restrict__ bias,
                                            float* __restrict__ out,
                                            int o, int Hin, int Win, int Wout,
                                            int stride, bool relu, int lane)
{
    int co  = o & 63;
    int pix = o >> 6;
    int ow  = pix % Wout;
    int oh  = pix / Wout;
    const float* wb = wgt + ((size_t)co * 64 + lane) * 9;
    float acc = 0.0f;
    #pragma unroll
    for (int kh = 0; kh < 3; ++kh) {
        int ih = oh * stride - 1 + kh;
        if (ih < 0 || ih >= Hin) continue;
        const float* ib = in + ((size_t)ih * Win) * 64 + lane;
        #pragma unroll
        for (int kw = 0; kw < 3; ++kw) {
            int iw = ow * stride - 1 + kw;
            if (iw < 0 || iw >= Win) continue;
            acc = fmaf(ib[(size_t)iw * 64], wb[kh * 3 + kw], acc);
        }
    }
    #pragma unroll
    for (int off = 32; off >= 1; off >>= 1)
        acc += __shfl_xor(acc, off, 64);
    if (lane == 0) {
        if (bias) acc += bias[co];
        if (relu) acc = fmaxf(acc, 0.0f);
        out[o] = acc;
    }
}

// L2: l1 || g1
__global__ void l1_g1_k(const float* __restrict__ splat,
                        const float* __restrict__ lw1, const float* __restrict__ lb1,
                        const float* __restrict__ gw1, const float* __restrict__ gb1,
                        float* __restrict__ l1, float* __restrict__ g1)
{
    int lane = threadIdx.x & 63;
    int W = (blockIdx.x * blockDim.x + threadIdx.x) >> 6;
    if (W < 32768) {
        int n = W >> 14, o = W & 16383;
        convw64_one(splat + (size_t)n * 16384, lw1, lb1, l1 + (size_t)n * 16384,
                    o, 16, 16, 16, 1, true, lane);
    } else {
        int W2 = W - 32768;
        if (W2 >= 8192) return;
        int n = W2 >> 12, o = W2 & 4095;
        convw64_one(splat + (size_t)n * 16384, gw1, gb1, g1 + (size_t)n * 4096,
                    o, 16, 16, 8, 2, true, lane);
    }
}

// L3: loc || g2
__global__ void loc_g2_k(const float* __restrict__ l1, const float* __restrict__ lw2,
                         const float* __restrict__ g1, const float* __restrict__ gw2,
                         const float* __restrict__ gb2,
                         float* __restrict__ loc, float* __restrict__ g2)
{
    int lane = threadIdx.x & 63;
    int W = (blockIdx.x * blockDim.x + threadIdx.x) >> 6;
    if (W < 32768) {
        int n = W >> 14, o = W & 16383;
        convw64_one(l1 + (size_t)n * 16384, lw2, nullptr, loc + (size_t)n * 16384,
                    o, 16, 16, 16, 1, false, lane);
    } else {
        int W2 = W - 32768;
        if (W2 >= 2048) return;
        int n = W2 >> 10, o = W2 & 1023;
        convw64_one(g1 + (size_t)n * 4096, gw2, gb2, g2 + (size_t)n * 1024,
                    o, 8, 8, 4, 2, true, lane);
    }
}

// ---------------------------------------------------------------------------
// L4: fcfusion96_k — 96 blocks x 1024 thr, split-K fc + fusion+pointwise.
// ---------------------------------------------------------------------------
__global__ void __launch_bounds__(1024) fcfusion96_k(
    const float* __restrict__ g2,
    const float* __restrict__ fwt3, const float* __restrict__ fb3,
    const float* __restrict__ fwt4, const float* __restrict__ fb4,
    const float* __restrict__ fwt5, const float* __restrict__ fb5,
    const float* __restrict__ loc,
    const float* __restrict__ pw, const float* __restrict__ pb,
    float* __restrict__ gridc)
{
    __shared__ float s_in[1024];
    __shared__ float s_p[1024];
    __shared__ float s_f3[256];
    __shared__ float s_f4[128];
    __shared__ float s_gl[64];

    const int tid = threadIdx.x;
    const int n   = blockIdx.x / 48;
    const int q   = blockIdx.x % 48;

    if (tid < 1024)
        s_in[tid] = g2[(size_t)n * 1024 + (tid & 15) * 64 + (tid >> 4)];
    __syncthreads();

    {
        int o = tid & 255, part = tid >> 8;
        const float* wp = fwt3 + (size_t)(part * 256) * 256 + o;
        const float* ip = s_in + part * 256;
        float acc = 0.0f;
        #pragma unroll 8
        for (int k = 0; k < 256; ++k)
            acc = fmaf(wp[k * 256], ip[k], acc);
        s_p[tid] = acc;
    }
    __syncthreads();
    if (tid < 256)
        s_f3[tid] = fmaxf(fb3[tid] + s_p[tid] + s_p[256 + tid] +
                          s_p[512 + tid] + s_p[768 + tid], 0.0f);
    __syncthreads();

    if (tid < 512) {
        int o = tid & 127, part = tid >> 7;
        const float* wp = fwt4 + (size_t)(part * 64) * 128 + o;
        const float* ip = s_f3 + part * 64;
        float acc = 0.0f;
        #pragma unroll 8
        for (int k = 0; k < 64; ++k)
            acc = fmaf(wp[k * 128], ip[k], acc);
        s_p[tid] = acc;
    }
    __syncthreads();
    if (tid < 128)
        s_f4[tid] = fmaxf(fb4[tid] + s_p[tid] + s_p[128 + tid] +
                          s_p[256 + tid] + s_p[384 + tid], 0.0f);
    __syncthreads();

    if (tid < 256) {
        int o = tid & 63, part = tid >> 6;
        const float* wp = fwt5 + (size_t)(part * 32) * 64 + o;
        const float* ip = s_f4 + part * 32;
        float acc = 0.0f;
        #pragma unroll 8
        for (int k = 0; k < 32; ++k)
            acc = fmaf(wp[k * 64], ip[k], acc);
        s_p[tid] = acc;
    }
    __syncthreads();
    if (tid < 64)
        s_gl[tid] = fb5[tid] + s_p[tid] + s_p[64 + tid] +
                    s_p[128 + tid] + s_p[192 + tid];
    __syncthreads();

    if (tid < 512) {
        int idx = q * 512 + tid;
        int c   = idx % 12;
        int zp  = idx / 12;
        int p   = zp & 255;
        int z   = zp >> 8;
        int co  = c * 8 + z;
        const float4* lp = (const float4*)(loc + ((size_t)n * 256 + p) * 64);
        const float4* gp = (const float4*)s_gl;
        const float4* wp = (const float4*)(pw + (size_t)co * 64);
        float acc = pb[co];
        #pragma unroll
        for (int i = 0; i < 16; ++i) {
            float4 l = lp[i], g = gp[i], w = wp[i];
            acc = fmaf(fmaxf(l.x + g.x, 0.0f), w.x, acc);
            acc = fmaf(fmaxf(l.y + g.y, 0.0f), w.y, acc);
            acc = fmaf(fmaxf(l.z + g.z, 0.0f), w.z, acc);
            acc = fmaf(fmaxf(l.w + g.w, 0.0f), w.w, acc);
        }
        gridc[(size_t)n * 24576 + idx] = acc;
    }
}

// ---------------------------------------------------------------------------
// L5: guide(LUT) + slice + apply, one block per row.
// ---------------------------------------------------------------------------
__global__ void __launch_bounds__(256) guide_slice_lut_k(
    const float* __restrict__ fullres,
    const float* __restrict__ gridc,
    const float2* __restrict__ lutg,
    const float* __restrict__ M, const float* __restrict__ Mb,
    const float* __restrict__ gbias,
    float* __restrict__ out)
{
    const int W = 1024, H = 1024;
    __shared__ float  ly[1536];
    __shared__ float2 lutS[3 * LUT_NB];

    int h = blockIdx.x & 1023;
    int n = blockIdx.x >> 10;

    float iy = fminf(fmaxf((float)h * (16.0f / (H - 1)) - 0.5f, 0.0f), 15.0f);
    float y0f = floorf(iy);
    float wy  = iy - y0f;
    int y0 = (int)y0f, y1 = min(y0 + 1, 15);

    const float* gn = gridc + (size_t)n * 24576;
    for (int i = threadIdx.x; i < 1536; i += 256) {
        int z   = i / 192;
        int rem = i - z * 192;
        float a = gn[z * 3072 + y0 * 192 + rem];
        float b = gn[z * 3072 + y1 * 192 + rem];
        ly[i] = fmaf(wy, b - a, a);
        lutS[i] = lutg[i];
    }
    __syncthreads();

    float M00 = M[0], M10 = M[3], M20 = M[6];
    float M01 = M[1], M11 = M[4], M21 = M[7];
    float M02 = M[2], M12 = M[5], M22 = M[8];
    float Mb0 = Mb[0], Mb1 = Mb[1], Mb2 = Mb[2];
    float gb  = gbias[0];

    int w0 = (int)threadIdx.x * 4;
    size_t plane = (size_t)H * W;
    size_t base  = (size_t)n * 3 * plane + (size_t)h * W + w0;
    float4 R  = *(const float4*)&fullres[base];
    float4 G  = *(const float4*)&fullres[base + plane];
    float4 Bc = *(const float4*)&fullres[base + 2 * plane];

    const float4* L = (const float4*)ly;

    float4 RR, GG, BB;
    float* rr = &RR.x; float* gg = &GG.x; float* bb = &BB.x;
    const float* rp = &R.x; const float* gp2 = &G.x; const float* bp = &Bc.x;

    #pragma unroll
    for (int p = 0; p < 4; ++p) {
        float r = rp[p], g = gp2[p], bc = bp[p];
        int w = w0 + p;

        float g0 = fmaf(r, M00, fmaf(g, M10, fmaf(bc, M20, Mb0)));
        float g1 = fmaf(r, M01, fmaf(g, M11, fmaf(bc, M21, Mb1)));
        float g2 = fmaf(r, M02, fmaf(g, M12, fmaf(bc, M22, Mb2)));
        float sum = 0.0f;
        {
            float t0 = fminf(fmaxf((g0 - LUT_LO) * LUT_INV, 0.0f), LUT_NB - 1.0f);
            int i0 = (int)t0; float f0 = t0 - (float)i0;
            float2 e0 = lutS[i0];
            sum += fmaf(f0, e0.y, e0.x);
            float t1 = fminf(fmaxf((g1 - LUT_LO) * LUT_INV, 0.0f), LUT_NB - 1.0f);
            int i1 = (int)t1; float f1 = t1 - (float)i1;
            float2 e1 = lutS[LUT_NB + i1];
            sum += fmaf(f1, e1.y, e1.x);
            float t2 = fminf(fmaxf((g2 - LUT_LO) * LUT_INV, 0.0f), LUT_NB - 1.0f);
            int i2 = (int)t2; float f2 = t2 - (float)i2;
            float2 e2 = lutS[2 * LUT_NB + i2];
            sum += fmaf(f2, e2.y, e2.x);
        }
        float guide = fminf(fmaxf(sum * (1.0f / 3.0f) + gb, 0.0f), 1.0f);

        float ix = fminf(fmaxf((float)w * (16.0f / (W - 1)) - 0.5f, 0.0f), 15.0f);
        float iz = fminf(fmaxf(8.0f * guide - 0.5f, 0.0f), 7.0f);
        float x0f = floorf(ix), z0f = floorf(iz);
        float wx = ix - x0f, wz = iz - z0f;
        int x0 = (int)x0f; int x1 = min(x0 + 1, 15);
        int z0 = (int)z0f; int z1 = min(z0 + 1, 7);
        float mx = 1.f - wx, mz = 1.f - wz;

        int n00 = (z0 * 16 + x0) * 3, n01 = (z0 * 16 + x1) * 3;
        int n10 = (z1 * 16 + x0) * 3, n11 = (z1 * 16 + x1) * 3;
        float W00 = mz * mx, W01 = mz * wx, W10 = wz * mx, W11 = wz * wx;

        float4 A0 = {0.f, 0.f, 0.f, 0.f}, A1 = A0, A2 = A0;
        auto nodeacc = [&](int nb, float wt) {
            float4 v0 = L[nb], v1 = L[nb + 1], v2 = L[nb + 2];
            A0.x = fmaf(wt, v0.x, A0.x); A0.y = fmaf(wt, v0.y, A0.y);
            A0.z = fmaf(wt, v0.z, A0.z); A0.w = fmaf(wt, v0.w, A0.w);
            A1.x = fmaf(wt, v1.x, A1.x); A1.y = fmaf(wt, v1.y, A1.y);
            A1.z = fmaf(wt, v1.z, A1.z); A1.w = fmaf(wt, v1.w, A1.w);
            A2.x = fmaf(wt, v2.x, A2.x); A2.y = fmaf(wt, v2.y, A2.y);
            A2.z = fmaf(wt, v2.z, A2.z); A2.w = fmaf(wt, v2.w, A2.w);
        };
        nodeacc(n00, W00);
        nodeacc(n01, W01);
        nodeacc(n10, W10);
        nodeacc(n11, W11);

        rr[p] = fmaf(r, A0.x, fmaf(g, A0.y, fmaf(bc, A0.z, A0.w)));
        gg[p] = fmaf(r, A1.x, fmaf(g, A1.y, fmaf(bc, A1.z, A1.w)));
        bb[p] = fmaf(r, A2.x, fmaf(g, A2.y, fmaf(bc, A2.z, A2.w)));
    }

    *(float4*)&out[base]             = RR;
    *(float4*)&out[base + plane]     = GG;
    *(float4*)&out[base + 2 * plane] = BB;
}

// ---------------------------------------------------------------------------
extern "C" void kernel_launch(void* const* d_in, const int* in_sizes, int n_in,
                              void* d_out, int out_size, void* d_ws, size_t ws_size,
                              hipStream_t stream)
{
    const float* lowres  = (const float*)d_in[0];
    const float* fullres = (const float*)d_in[1];
    const float* sw1 = (const float*)d_in[2];  const float* sb1 = (const float*)d_in[3];
    const float* sw2 = (const float*)d_in[4];  const float* sb2 = (const float*)d_in[5];
    const float* sw3 = (const float*)d_in[6];  const float* sb3 = (const float*)d_in[7];
    const float* sw4 = (const float*)d_in[8];  const float* sb4 = (const float*)d_in[9];
    const float* gw1 = (const float*)d_in[10]; const float* gb1 = (const float*)d_in[11];
    const float* gw2 = (const float*)d_in[12]; const float* gb2 = (const float*)d_in[13];
    const float* fw3 = (const float*)d_in[14]; const float* fb3 = (const float*)d_in[15];
    const float* fw4 = (const float*)d_in[16]; const float* fb4 = (const float*)d_in[17];
    const float* fw5 = (const float*)d_in[18]; const float* fb5 = (const float*)d_in[19];
    const float* lw1 = (const float*)d_in[20]; const float* lb1 = (const float*)d_in[21];
    const float* lw2 = (const float*)d_in[22];
    const float* pw  = (const float*)d_in[23]; const float* pb  = (const float*)d_in[24];
    const float* M   = (const float*)d_in[25]; const float* Mb  = (const float*)d_in[26];
    const float* thr = (const float*)d_in[27]; const float* slp = (const float*)d_in[28];
    const float* gbias = (const float*)d_in[29];

    float* ws    = (float*)d_ws;
    float* splat = ws;              // HWC [2][16][16][64]  = 32768
    float* g1    = splat + 32768;   // HWC [2][8][8][64]    = 8192
    float* g2    = g1 + 8192;       // HWC [2][4][4][64]    = 2048
    float* l1    = g2 + 2048;       // HWC [2][16][16][64]  = 32768
    float* loc   = l1 + 32768;      // HWC [2][16][16][64]  = 32768
    float* gridc = loc + 32768;     // [2][8][16][16][12]   = 49152
    float2* lutg = (float2*)(gridc + 49152);
    float* fwt3  = (float*)(lutg + 1536);      // [1024][256]
    float* fwt4  = fwt3 + 262144;   // [256][128]
    float* fwt5  = fwt4 + 32768;    // [128][64]

    // L1: conv1+conv2+conv3+conv4 (+LUT, +fc transposes)
    conv1234_k<<<512, 256, 0, stream>>>(lowres, sw1, sb1, sw2, sb2, sw3, sb3,
        sw4, sb4, thr, slp, fw3, fw4, fw5, splat, lutg, fwt3, fwt4, fwt5);
    // L2: l1 || g1
    l1_g1_k<<<10240, 256, 0, stream>>>(splat, lw1, lb1, gw1, gb1, l1, g1);
    // L3: loc || g2
    loc_g2_k<<<8704, 256, 0, stream>>>(l1, lw2, g1, gw2, gb2, loc, g2);
    // L4: fc chain + fusion + pointwise
    fcfusion96_k<<<96, 1024, 0, stream>>>(g2, fwt3, fb3, fwt4, fb4, fwt5, fb5,
        loc, pw, pb, gridc);
    // L5: guide + slice + apply
    guide_slice_lut_k<<<2048, 256, 0, stream>>>(fullres, gridc, lutg, M, Mb,
        gbias, (float*)d_out);
}

// Round 20
// 107.350 us; speedup vs baseline: 1.2093x; 1.2093x over previous
//
#include <hip/hip_runtime.h>

// ===========================================================================
// R20: R18 structure (best, 117.3us) + conv123 phase-A rebuilt: lowres tile
// staged to LDS (coalesced, zero-padded) before conv1, removing the ~26K
// scattered branch-guarded global loads per block that R19 showed dominate
// the conv chain (~43us of R18).
// 6 levels: conv123, conv4, l1||g1, loc||g2, fcfusion96, slice.
// Ledger: ~12us/level; WIDE beats fused-narrow; level = slowest block; no
// heterogeneous VGPR/LDS fusion (R17); no serial wave-reduce chains (R10);
// no grid.sync (R7); transposed FC weights + waves (R12-R14); stage scattered
// input reads through LDS (R19/R20).
// ===========================================================================

#define LUT_NB   512
#define LUT_LO   (-0.25f)
#define LUT_BIN  (1.5f / LUT_NB)
#define LUT_INV  (LUT_NB / 1.5f)

// ---------------------------------------------------------------------------
// L1: conv1+conv2+conv3 halo-fused with LDS-staged lowres tile.
// Block = (n, 2x2 x3-tile). 512 blocks.
// ---------------------------------------------------------------------------
__global__ void __launch_bounds__(256) conv123_k(
    const float* __restrict__ lowres,
    const float* __restrict__ sw1, const float* __restrict__ sb1,
    const float* __restrict__ sw2, const float* __restrict__ sb2,
    const float* __restrict__ sw3, const float* __restrict__ sb3,
    const float* __restrict__ thr, const float* __restrict__ slp,
    const float* __restrict__ fw3, const float* __restrict__ fw4,
    const float* __restrict__ fw5,
    float* __restrict__ x3, float2* __restrict__ lut,
    float* __restrict__ fwt3, float* __restrict__ fwt4,
    float* __restrict__ fwt5)
{
    __shared__ float s_low[3 * 23 * 23];   // 6.2KB  [ci][23][23]
    __shared__ float s_x1[11 * 11 * 8];    // 3.9KB
    __shared__ float s_x2[5 * 5 * 16];     // 1.6KB
    const int tid  = threadIdx.x;
    const int n    = blockIdx.x >> 8;
    const int tile = blockIdx.x & 255;
    const int ty   = tile >> 4, tx = tile & 15;

    // ---- one-time weight transposes (spread over 512 blocks) ----
    {
        int tg = blockIdx.x * 256 + tid;           // 0..131071
        #pragma unroll
        for (int r = 0; r < 2; ++r) {
            int e = tg + r * 131072;
            int o = e & 255, k = e >> 8;
            fwt3[e] = fw3[o * 1024 + k];
        }
        if (tg < 32768) {
            int o = tg & 127, k = tg >> 7;
            fwt4[tg] = fw4[o * 256 + k];
        }
        if (tg < 8192) {
            int o = tg & 63, k = tg >> 6;
            fwt5[tg] = fw5[o * 128 + k];
        }
    }
    if (blockIdx.x == 0) {
        for (int e = tid; e < 3 * LUT_NB; e += 256) {
            int j = e >> 9;
            int i = e & (LUT_NB - 1);
            float xl = LUT_LO + i * LUT_BIN;
            float xh = xl + LUT_BIN;
            float a = 0.0f, c = 0.0f;
            #pragma unroll
            for (int k = 0; k < 16; ++k) {
                float tt = thr[j * 16 + k], ss = slp[j * 16 + k];
                a = fmaf(ss, fmaxf(xl - tt, 0.0f), a);
                c = fmaf(ss, fmaxf(xh - tt, 0.0f), c);
            }
            lut[e] = make_float2(a, c - a);
        }
    }

    const int b1h = 8 * ty - 3, b1w = 8 * tx - 3;   // x1 halo origin (11)
    const int b2h = 4 * ty - 1, b2w = 4 * tx - 1;   // x2 halo origin (5)
    const int r0  = 2 * b1h - 1, c0 = 2 * b1w - 1;  // lowres tile origin (23)

    // Phase A0: stage lowres tile [3][23][23] (coalesced rows, zero-padded)
    for (int i = tid; i < 1587; i += 256) {
        int ci  = i / 529;
        int rem = i - ci * 529;
        int lh  = rem / 23, lw = rem - lh * 23;
        int ih  = r0 + lh, iw = c0 + lw;
        float v = 0.0f;
        if (ih >= 0 && ih < 256 && iw >= 0 && iw < 256)
            v = lowres[((size_t)(n * 3 + ci)) * 65536 + ih * 256 + iw];
        s_low[i] = v;
    }
    __syncthreads();

    // Phase A: x1 halo 11x11x8 (conv1 from s_low; branch-free inner loop)
    for (int i = tid; i < 968; i += 256) {
        int c   = i & 7;
        int pos = i >> 3;
        int lw  = pos % 11, lh = pos / 11;
        int gh  = b1h + lh, gw = b1w + lw;
        float v = 0.0f;
        if (gh >= 0 && gh < 128 && gw >= 0 && gw < 128) {
            float acc = sb1[c];
            const float* wc = sw1 + c * 27;
            #pragma unroll
            for (int ci = 0; ci < 3; ++ci) {
                const float* xp = &s_low[ci * 529 + (2 * lh) * 23 + 2 * lw];
                const float* wp = wc + ci * 9;
                #pragma unroll
                for (int kh = 0; kh < 3; ++kh) {
                    #pragma unroll
                    for (int kw = 0; kw < 3; ++kw)
                        acc = fmaf(xp[kh * 23 + kw], wp[kh * 3 + kw], acc);
                }
            }
            v = fmaxf(acc, 0.0f);
        }
        s_x1[i] = v;
    }
    __syncthreads();

    // Phase B: x2 halo 5x5x16 (conv2 from s_x1)
    for (int i = tid; i < 400; i += 256) {
        int c   = i & 15;
        int pos = i >> 4;
        int lw  = pos % 5, lh = pos / 5;
        int gh  = b2h + lh, gw = b2w + lw;
        float v = 0.0f;
        if (gh >= 0 && gh < 64 && gw >= 0 && gw < 64) {
            float acc = sb2[c];
            const float* wb = sw2 + (size_t)c * 72;
            #pragma unroll
            for (int kh = 0; kh < 3; ++kh) {
                #pragma unroll
                for (int kw = 0; kw < 3; ++kw) {
                    const float* xp = &s_x1[((2 * lh + kh) * 11 + 2 * lw + kw) * 8];
                    const float* wp = wb + kh * 3 + kw;
                    #pragma unroll
                    for (int ci = 0; ci < 8; ++ci)
                        acc = fmaf(xp[ci], wp[ci * 9], acc);
                }
            }
            v = fmaxf(acc, 0.0f);
        }
        s_x2[i] = v;
    }
    __syncthreads();

    // Phase C: x3 2x2x32 (conv3 from s_x2) -> global HWC
    if (tid < 128) {
        int c   = tid & 31;
        int pos = tid >> 5;
        int lh  = pos >> 1, lw = pos & 1;
        int gh  = 2 * ty + lh, gw = 2 * tx + lw;
        float acc = sb3[c];
        const float* wb = sw3 + (size_t)c * 144;
        #pragma unroll
        for (int kh = 0; kh < 3; ++kh) {
            #pragma unroll
            for (int kw = 0; kw < 3; ++kw) {
                const float* xp = &s_x2[((2 * lh + kh) * 5 + 2 * lw + kw) * 16];
                const float* wp = wb + kh * 3 + kw;
                #pragma unroll
                for (int ci = 0; ci < 16; ++ci)
                    acc = fmaf(xp[ci], wp[ci * 9], acc);
            }
        }
        x3[((size_t)(n * 32 + gh) * 32 + gw) * 32 + c] = fmaxf(acc, 0.0f);
    }
}

// ---------------------------------------------------------------------------
// Wave conv, HWC, lane = input channel, one subgroup reduce per wave.
// ---------------------------------------------------------------------------
template <int CIN>
__global__ void convw_hwc_k(const float* __restrict__ in, const float* __restrict__ w,
                            const float* __restrict__ b, float* __restrict__ out,
                            int N, int Hin, int Win, int Cout, int Hout, int Wout,
                            int stride, int do_relu)
{
    constexpr int OPW = 64 / CIN;
    int lane = threadIdx.x & 63;
    int wid  = (blockIdx.x * blockDim.x + threadIdx.x) >> 6;
    int sub  = lane / CIN;
    int cl   = lane % CIN;
    int o    = wid * OPW + sub;
    int total = N * Hout * Wout * Cout;

    float acc = 0.0f;
    if (o < total) {
        int co  = o % Cout;
        int pix = o / Cout;
        int ow  = pix % Wout;
        int oh  = (pix / Wout) % Hout;
        int n   = pix / (Wout * Hout);
        const float* wb = w + ((size_t)co * CIN + cl) * 9;
        #pragma unroll
        for (int kh = 0; kh < 3; ++kh) {
            int ih = oh * stride - 1 + kh;
            if (ih < 0 || ih >= Hin) continue;
            const float* ib = in + (((size_t)(n * Hin + ih)) * Win) * CIN + cl;
            #pragma unroll
            for (int kw = 0; kw < 3; ++kw) {
                int iw = ow * stride - 1 + kw;
                if (iw < 0 || iw >= Win) continue;
                acc = fmaf(ib[(size_t)iw * CIN], wb[kh * 3 + kw], acc);
            }
        }
    }
    #pragma unroll
    for (int off = CIN / 2; off >= 1; off >>= 1)
        acc += __shfl_xor(acc, off, 64);

    if (o < total && cl == 0) {
        if (b) acc += b[o % Cout];
        if (do_relu) acc = fmaxf(acc, 0.0f);
        out[o] = acc;
    }
}

// ---------------------------------------------------------------------------
// CIN=64 wave-conv, ONE output per wave.
// ---------------------------------------------------------------------------
__device__ __forceinline__ void convw64_one(const float* __restrict__ in,
                                            const float* __restrict__ wgt,
                                            const float* __restrict__ bias,
                                            float* __restrict__ out,
                                            int o, int Hin, int Win, int Wout,
                                            int stride, bool relu, int lane)
{
    int co  = o & 63;
    int pix = o >> 6;
    int ow  = pix % Wout;
    int oh  = pix / Wout;
    const float* wb = wgt + ((size_t)co * 64 + lane) * 9;
    float acc = 0.0f;
    #pragma unroll
    for (int kh = 0; kh < 3; ++kh) {
        int ih = oh * stride - 1 + kh;
        if (ih < 0 || ih >= Hin) continue;
        const float* ib = in + ((size_t)ih * Win) * 64 + lane;
        #pragma unroll
        for (int kw = 0; kw < 3; ++kw) {
            int iw = ow * stride - 1 + kw;
            if (iw < 0 || iw >= Win) continue;
            acc = fmaf(ib[(size_t)iw * 64], wb[kh * 3 + kw], acc);
        }
    }
    #pragma unroll
    for (int off = 32; off >= 1; off >>= 1)
        acc += __shfl_xor(acc, off, 64);
    if (lane == 0) {
        if (bias) acc += bias[co];
        if (relu) acc = fmaxf(acc, 0.0f);
        out[o] = acc;
    }
}

// L3: l1 || g1
__global__ void l1_g1_k(const float* __restrict__ splat,
                        const float* __restrict__ lw1, const float* __restrict__ lb1,
                        const float* __restrict__ gw1, const float* __restrict__ gb1,
                        float* __restrict__ l1, float* __restrict__ g1)
{
    int lane = threadIdx.x & 63;
    int W = (blockIdx.x * blockDim.x + threadIdx.x) >> 6;
    if (W < 32768) {
        int n = W >> 14, o = W & 16383;
        convw64_one(splat + (size_t)n * 16384, lw1, lb1, l1 + (size_t)n * 16384,
                    o, 16, 16, 16, 1, true, lane);
    } else {
        int W2 = W - 32768;
        if (W2 >= 8192) return;
        int n = W2 >> 12, o = W2 & 4095;
        convw64_one(splat + (size_t)n * 16384, gw1, gb1, g1 + (size_t)n * 4096,
                    o, 16, 16, 8, 2, true, lane);
    }
}

// L4: loc || g2
__global__ void loc_g2_k(const float* __restrict__ l1, const float* __restrict__ lw2,
                         const float* __restrict__ g1, const float* __restrict__ gw2,
                         const float* __restrict__ gb2,
                         float* __restrict__ loc, float* __restrict__ g2)
{
    int lane = threadIdx.x & 63;
    int W = (blockIdx.x * blockDim.x + threadIdx.x) >> 6;
    if (W < 32768) {
        int n = W >> 14, o = W & 16383;
        convw64_one(l1 + (size_t)n * 16384, lw2, nullptr, loc + (size_t)n * 16384,
                    o, 16, 16, 16, 1, false, lane);
    } else {
        int W2 = W - 32768;
        if (W2 >= 2048) return;
        int n = W2 >> 10, o = W2 & 1023;
        convw64_one(g1 + (size_t)n * 4096, gw2, gb2, g2 + (size_t)n * 1024,
                    o, 8, 8, 4, 2, true, lane);
    }
}

// ---------------------------------------------------------------------------
// L5: fcfusion96_k — 96 blocks x 1024 thr, split-K fc + fusion+pointwise.
// ---------------------------------------------------------------------------
__global__ void __launch_bounds__(1024) fcfusion96_k(
    const float* __restrict__ g2,
    const float* __restrict__ fwt3, const float* __restrict__ fb3,
    const float* __restrict__ fwt4, const float* __restrict__ fb4,
    const float* __restrict__ fwt5, const float* __restrict__ fb5,
    const float* __restrict__ loc,
    const float* __restrict__ pw, const float* __restrict__ pb,
    float* __restrict__ gridc)
{
    __shared__ float s_in[1024];
    __shared__ float s_p[1024];
    __shared__ float s_f3[256];
    __shared__ float s_f4[128];
    __shared__ float s_gl[64];

    const int tid = threadIdx.x;
    const int n   = blockIdx.x / 48;
    const int q   = blockIdx.x % 48;

    if (tid < 1024)
        s_in[tid] = g2[(size_t)n * 1024 + (tid & 15) * 64 + (tid >> 4)];
    __syncthreads();

    {
        int o = tid & 255, part = tid >> 8;
        const float* wp = fwt3 + (size_t)(part * 256) * 256 + o;
        const float* ip = s_in + part * 256;
        float acc = 0.0f;
        #pragma unroll 8
        for (int k = 0; k < 256; ++k)
            acc = fmaf(wp[k * 256], ip[k], acc);
        s_p[tid] = acc;
    }
    __syncthreads();
    if (tid < 256)
        s_f3[tid] = fmaxf(fb3[tid] + s_p[tid] + s_p[256 + tid] +
                          s_p[512 + tid] + s_p[768 + tid], 0.0f);
    __syncthreads();

    if (tid < 512) {
        int o = tid & 127, part = tid >> 7;
        const float* wp = fwt4 + (size_t)(part * 64) * 128 + o;
        const float* ip = s_f3 + part * 64;
        float acc = 0.0f;
        #pragma unroll 8
        for (int k = 0; k < 64; ++k)
            acc = fmaf(wp[k * 128], ip[k], acc);
        s_p[tid] = acc;
    }
    __syncthreads();
    if (tid < 128)
        s_f4[tid] = fmaxf(fb4[tid] + s_p[tid] + s_p[128 + tid] +
                          s_p[256 + tid] + s_p[384 + tid], 0.0f);
    __syncthreads();

    if (tid < 256) {
        int o = tid & 63, part = tid >> 6;
        const float* wp = fwt5 + (size_t)(part * 32) * 64 + o;
        const float* ip = s_f4 + part * 32;
        float acc = 0.0f;
        #pragma unroll 8
        for (int k = 0; k < 32; ++k)
            acc = fmaf(wp[k * 64], ip[k], acc);
        s_p[tid] = acc;
    }
    __syncthreads();
    if (tid < 64)
        s_gl[tid] = fb5[tid] + s_p[tid] + s_p[64 + tid] +
                    s_p[128 + tid] + s_p[192 + tid];
    __syncthreads();

    if (tid < 512) {
        int idx = q * 512 + tid;
        int c   = idx % 12;
        int zp  = idx / 12;
        int p   = zp & 255;
        int z   = zp >> 8;
        int co  = c * 8 + z;
        const float4* lp = (const float4*)(loc + ((size_t)n * 256 + p) * 64);
        const float4* gp = (const float4*)s_gl;
        const float4* wp = (const float4*)(pw + (size_t)co * 64);
        float acc = pb[co];
        #pragma unroll
        for (int i = 0; i < 16; ++i) {
            float4 l = lp[i], g = gp[i], w = wp[i];
            acc = fmaf(fmaxf(l.x + g.x, 0.0f), w.x, acc);
            acc = fmaf(fmaxf(l.y + g.y, 0.0f), w.y, acc);
            acc = fmaf(fmaxf(l.z + g.z, 0.0f), w.z, acc);
            acc = fmaf(fmaxf(l.w + g.w, 0.0f), w.w, acc);
        }
        gridc[(size_t)n * 24576 + idx] = acc;
    }
}

// ---------------------------------------------------------------------------
// L6: guide(LUT) + slice + apply, one block per row.
// ---------------------------------------------------------------------------
__global__ void __launch_bounds__(256) guide_slice_lut_k(
    const float* __restrict__ fullres,
    const float* __restrict__ gridc,
    const float2* __restrict__ lutg,
    const float* __restrict__ M, const float* __restrict__ Mb,
    const float* __restrict__ gbias,
    float* __restrict__ out)
{
    const int W = 1024, H = 1024;
    __shared__ float  ly[1536];
    __shared__ float2 lutS[3 * LUT_NB];

    int h = blockIdx.x & 1023;
    int n = blockIdx.x >> 10;

    float iy = fminf(fmaxf((float)h * (16.0f / (H - 1)) - 0.5f, 0.0f), 15.0f);
    float y0f = floorf(iy);
    float wy  = iy - y0f;
    int y0 = (int)y0f, y1 = min(y0 + 1, 15);

    const float* gn = gridc + (size_t)n * 24576;
    for (int i = threadIdx.x; i < 1536; i += 256) {
        int z   = i / 192;
        int rem = i - z * 192;
        float a = gn[z * 3072 + y0 * 192 + rem];
        float b = gn[z * 3072 + y1 * 192 + rem];
        ly[i] = fmaf(wy, b - a, a);
        lutS[i] = lutg[i];
    }
    __syncthreads();

    float M00 = M[0], M10 = M[3], M20 = M[6];
    float M01 = M[1], M11 = M[4], M21 = M[7];
    float M02 = M[2], M12 = M[5], M22 = M[8];
    float Mb0 = Mb[0], Mb1 = Mb[1], Mb2 = Mb[2];
    float gb  = gbias[0];

    int w0 = (int)threadIdx.x * 4;
    size_t plane = (size_t)H * W;
    size_t base  = (size_t)n * 3 * plane + (size_t)h * W + w0;
    float4 R  = *(const float4*)&fullres[base];
    float4 G  = *(const float4*)&fullres[base + plane];
    float4 Bc = *(const float4*)&fullres[base + 2 * plane];

    const float4* L = (const float4*)ly;

    float4 RR, GG, BB;
    float* rr = &RR.x; float* gg = &GG.x; float* bb = &BB.x;
    const float* rp = &R.x; const float* gp2 = &G.x; const float* bp = &Bc.x;

    #pragma unroll
    for (int p = 0; p < 4; ++p) {
        float r = rp[p], g = gp2[p], bc = bp[p];
        int w = w0 + p;

        float g0 = fmaf(r, M00, fmaf(g, M10, fmaf(bc, M20, Mb0)));
        float g1 = fmaf(r, M01, fmaf(g, M11, fmaf(bc, M21, Mb1)));
        float g2 = fmaf(r, M02, fmaf(g, M12, fmaf(bc, M22, Mb2)));
        float sum = 0.0f;
        {
            float t0 = fminf(fmaxf((g0 - LUT_LO) * LUT_INV, 0.0f), LUT_NB - 1.0f);
            int i0 = (int)t0; float f0 = t0 - (float)i0;
            float2 e0 = lutS[i0];
            sum += fmaf(f0, e0.y, e0.x);
            float t1 = fminf(fmaxf((g1 - LUT_LO) * LUT_INV, 0.0f), LUT_NB - 1.0f);
            int i1 = (int)t1; float f1 = t1 - (float)i1;
            float2 e1 = lutS[LUT_NB + i1];
            sum += fmaf(f1, e1.y, e1.x);
            float t2 = fminf(fmaxf((g2 - LUT_LO) * LUT_INV, 0.0f), LUT_NB - 1.0f);
            int i2 = (int)t2; float f2 = t2 - (float)i2;
            float2 e2 = lutS[2 * LUT_NB + i2];
            sum += fmaf(f2, e2.y, e2.x);
        }
        float guide = fminf(fmaxf(sum * (1.0f / 3.0f) + gb, 0.0f), 1.0f);

        float ix = fminf(fmaxf((float)w * (16.0f / (W - 1)) - 0.5f, 0.0f), 15.0f);
        float iz = fminf(fmaxf(8.0f * guide - 0.5f, 0.0f), 7.0f);
        float x0f = floorf(ix), z0f = floorf(iz);
        float wx = ix - x0f, wz = iz - z0f;
        int x0 = (int)x0f; int x1 = min(x0 + 1, 15);
        int z0 = (int)z0f; int z1 = min(z0 + 1, 7);
        float mx = 1.f - wx, mz = 1.f - wz;

        int n00 = (z0 * 16 + x0) * 3, n01 = (z0 * 16 + x1) * 3;
        int n10 = (z1 * 16 + x0) * 3, n11 = (z1 * 16 + x1) * 3;
        float W00 = mz * mx, W01 = mz * wx, W10 = wz * mx, W11 = wz * wx;

        float4 A0 = {0.f, 0.f, 0.f, 0.f}, A1 = A0, A2 = A0;
        auto nodeacc = [&](int nb, float wt) {
            float4 v0 = L[nb], v1 = L[nb + 1], v2 = L[nb + 2];
            A0.x = fmaf(wt, v0.x, A0.x); A0.y = fmaf(wt, v0.y, A0.y);
            A0.z = fmaf(wt, v0.z, A0.z); A0.w = fmaf(wt, v0.w, A0.w);
            A1.x = fmaf(wt, v1.x, A1.x); A1.y = fmaf(wt, v1.y, A1.y);
            A1.z = fmaf(wt, v1.z, A1.z); A1.w = fmaf(wt, v1.w, A1.w);
            A2.x = fmaf(wt, v2.x, A2.x); A2.y = fmaf(wt, v2.y, A2.y);
            A2.z = fmaf(wt, v2.z, A2.z); A2.w = fmaf(wt, v2.w, A2.w);
        };
        nodeacc(n00, W00);
        nodeacc(n01, W01);
        nodeacc(n10, W10);
        nodeacc(n11, W11);

        rr[p] = fmaf(r, A0.x, fmaf(g, A0.y, fmaf(bc, A0.z, A0.w)));
        gg[p] = fmaf(r, A1.x, fmaf(g, A1.y, fmaf(bc, A1.z, A1.w)));
        bb[p] = fmaf(r, A2.x, fmaf(g, A2.y, fmaf(bc, A2.z, A2.w)));
    }

    *(float4*)&out[base]             = RR;
    *(float4*)&out[base + plane]     = GG;
    *(float4*)&out[base + 2 * plane] = BB;
}

// ---------------------------------------------------------------------------
extern "C" void kernel_launch(void* const* d_in, const int* in_sizes, int n_in,
                              void* d_out, int out_size, void* d_ws, size_t ws_size,
                              hipStream_t stream)
{
    const float* lowres  = (const float*)d_in[0];
    const float* fullres = (const float*)d_in[1];
    const float* sw1 = (const float*)d_in[2];  const float* sb1 = (const float*)d_in[3];
    const float* sw2 = (const float*)d_in[4];  const float* sb2 = (const float*)d_in[5];
    const float* sw3 = (const float*)d_in[6];  const float* sb3 = (const float*)d_in[7];
    const float* sw4 = (const float*)d_in[8];  const float* sb4 = (const float*)d_in[9];
    const float* gw1 = (const float*)d_in[10]; const float* gb1 = (const float*)d_in[11];
    const float* gw2 = (const float*)d_in[12]; const float* gb2 = (const float*)d_in[13];
    const float* fw3 = (const float*)d_in[14]; const float* fb3 = (const float*)d_in[15];
    const float* fw4 = (const float*)d_in[16]; const float* fb4 = (const float*)d_in[17];
    const float* fw5 = (const float*)d_in[18]; const float* fb5 = (const float*)d_in[19];
    const float* lw1 = (const float*)d_in[20]; const float* lb1 = (const float*)d_in[21];
    const float* lw2 = (const float*)d_in[22];
    const float* pw  = (const float*)d_in[23]; const float* pb  = (const float*)d_in[24];
    const float* M   = (const float*)d_in[25]; const float* Mb  = (const float*)d_in[26];
    const float* thr = (const float*)d_in[27]; const float* slp = (const float*)d_in[28];
    const float* gbias = (const float*)d_in[29];

    const int N = 2, B = 256;
    auto wblk = [](int total_out, int opw) {
        int waves = (total_out + opw - 1) / opw;
        return (waves * 64 + 255) / 256;
    };

    float* ws    = (float*)d_ws;
    float* x3    = ws;              // HWC [2][32][32][32]  = 65536
    float* splat = x3 + 65536;      // HWC [2][16][16][64]  = 32768
    float* g1    = splat + 32768;   // HWC [2][8][8][64]    = 8192
    float* g2    = g1 + 8192;       // HWC [2][4][4][64]    = 2048
    float* l1    = g2 + 2048;       // HWC [2][16][16][64]  = 32768
    float* loc   = l1 + 32768;      // HWC [2][16][16][64]  = 32768
    float* gridc = loc + 32768;     // [2][8][16][16][12]   = 49152
    float2* lutg = (float2*)(gridc + 49152);
    float* fwt3  = (float*)(lutg + 1536);      // [1024][256]
    float* fwt4  = fwt3 + 262144;   // [256][128]
    float* fwt5  = fwt4 + 32768;    // [128][64]

    // L1: conv1+conv2+conv3 (LDS-staged lowres; +LUT, +fc transposes)
    conv123_k<<<512, 256, 0, stream>>>(lowres, sw1, sb1, sw2, sb2, sw3, sb3,
        thr, slp, fw3, fw4, fw5, x3, lutg, fwt3, fwt4, fwt5);
    // L2: conv4 (wide wave-conv)
    convw_hwc_k<32><<<wblk(2*16*16*64, 2), B, 0, stream>>>(x3, sw4, sb4, splat,
        N, 32, 32, 64, 16, 16, 2, 1);
    // L3: l1 || g1
    l1_g1_k<<<10240, 256, 0, stream>>>(splat, lw1, lb1, gw1, gb1, l1, g1);
    // L4: loc || g2
    loc_g2_k<<<8704, 256, 0, stream>>>(l1, lw2, g1, gw2, gb2, loc, g2);
    // L5: fc chain + fusion + pointwise
    fcfusion96_k<<<96, 1024, 0, stream>>>(g2, fwt3, fb3, fwt4, fb4, fwt5, fb5,
        loc, pw, pb, gridc);
    // L6: guide + slice + apply
    guide_slice_lut_k<<<2048, 256, 0, stream>>>(fullres, gridc, lutg, M, Mb,
        gbias, (float*)d_out);
}